// Round 1
// baseline (70.798 us; speedup 1.0000x reference)
//
#include <hip/hip_runtime.h>
#include <math.h>

namespace {

constexpr int kB = 16, kT = 50, kH = 96, kW = 96, kA = 5, kC = 8;
constexpr int kCH = 7 + kC;                    // 15 channels per anchor
constexpr int kPlane = kH * kW;                // 9216
constexpr int kPerImg = kA * kPlane;           // 46080
constexpr int kBlk = 256;
constexpr int kBlocksPerImg = kPerImg / kBlk;  // 180 (exact: 46080 % 256 == 0)
constexpr float kThresh = 0.6f;
constexpr float kObjSq = 100.0f;               // OBJ^2

__device__ __forceinline__ float sigmoidf(float v) {
  return 1.0f / (1.0f + expf(-v));
}

// Kernel A: zero the accumulators (d_out is NOT re-zeroed between timed
// replays) and compute nGT = sum of cumprod-valid targets.
__global__ void prep_kernel(const float* __restrict__ tgt,
                            float* __restrict__ d_out) {
  __shared__ int s_cnt[kB];
  const int tid = threadIdx.x;
  if (tid < kB) {
    bool ok = true;
    int cnt = 0;
    for (int t = 0; t < kT; ++t) {
      float g1 = tgt[(tid * kT + t) * 7 + 1];
      ok = ok && (g1 != 0.0f);
      cnt += ok ? 1 : 0;
    }
    s_cnt[tid] = cnt;
  }
  __syncthreads();
  if (tid == 0) {
    int tot = 0;
    for (int b = 0; b < kB; ++b) tot += s_cnt[b];
    d_out[0] = 0.0f;        // loss accumulator
    d_out[1] = 0.0f;        // nCorrect accumulator
    d_out[2] = (float)tot;  // nGT
  }
}

// Kernel B: one thread per prediction cell; per-block LDS target prep.
__global__ __launch_bounds__(kBlk) void loss_kernel(
    const float* __restrict__ out, const float* __restrict__ tgt,
    const float* __restrict__ anc, float* __restrict__ d_out) {
  __shared__ int s_idx[kT];   // flat scatter index, -1 if invalid
  __shared__ float s_gx[kT], s_gy[kT], s_gw[kT], s_gl[kT];
  __shared__ float s_tx[kT], s_ty[kT], s_tw[kT], s_tl[kT], s_tim[kT], s_tre[kT];
  __shared__ int s_tc[kT];
  __shared__ float s_aw[kA], s_ah[kA];
  __shared__ float s_red[kBlk / 64];
  __shared__ int s_redi[kBlk / 64];

  const int tid = threadIdx.x;
  const int b = blockIdx.x / kBlocksPerImg;
  const int nloc = (blockIdx.x % kBlocksPerImg) * kBlk + tid;

  // anchors -> LDS (wave 1 lanes)
  if (tid >= 64 && tid < 64 + kA) {
    int a0 = tid - 64;
    s_aw[a0] = anc[2 * a0];
    s_ah[a0] = anc[2 * a0 + 1];
  }

  // wave 0: per-target prep (valid = cumprod of (g1 != 0) via ballot prefix)
  if (tid < 64) {
    const int t = tid;
    const float* tp = tgt + (b * kT + (t < kT ? t : 0)) * 7;
    float c0 = tp[0], g1 = tp[1], g2 = tp[2], g3 = tp[3], g4 = tp[4];
    float e5 = tp[5], e6 = tp[6];
    unsigned long long nzm = __ballot((t < kT) && (g1 != 0.0f));
    if (t < kT) {
      unsigned long long pre = (1ull << (t + 1)) - 1ull;  // t+1 <= 50
      bool valid = ((~nzm) & pre) == 0ull;
      float gx = g1 * kW, gy = g2 * kH, gw = g3 * kW, gl = g4 * kH;
      float garea = gw * gl;
      float best = -1.0f;
      int bn = 0;
      for (int a = 0; a < kA; ++a) {
        float aw = anc[2 * a], ah = anc[2 * a + 1];
        float inter = fminf(gw, aw) * fminf(gl, ah);
        float iou = inter / (garea + aw * ah - inter);
        if (iou > best) { best = iou; bn = a; }  // first max wins (argmax)
      }
      int gi = min(max((int)gx, 0), kW - 1);
      int gj = min(max((int)gy, 0), kH - 1);
      int idx = ((b * kA + bn) * kH + gj) * kW + gi;
      s_idx[t] = valid ? idx : -1;
      s_gx[t] = gx; s_gy[t] = gy; s_gw[t] = gw; s_gl[t] = gl;
      s_tx[t] = gx - (float)gi;
      s_ty[t] = gy - (float)gj;
      s_tw[t] = logf(gw / anc[2 * bn]);
      s_tl[t] = logf(gl / anc[2 * bn + 1]);
      s_tim[t] = e5;
      s_tre[t] = e6;
      s_tc[t] = (int)c0;
    }
  }
  __syncthreads();

  const int a = nloc / kPlane;  // block-uniform (9216 % 256 == 0)
  const int rem = nloc % kPlane;
  const int j = rem / kW;
  const int i = rem % kW;
  const int n_global = b * kPerImg + nloc;

  const float* p = out + (size_t)(b * kA + a) * kCH * kPlane + rem;
  const float xr = p[0 * kPlane];
  const float yr = p[1 * kPlane];
  const float w  = p[2 * kPlane];
  const float l  = p[3 * kPlane];
  const float im = p[4 * kPlane];
  const float re = p[5 * kPlane];
  const float cr = p[6 * kPlane];
  const float c0v = p[7 * kPlane],  c1v = p[8 * kPlane];
  const float c2v = p[9 * kPlane],  c3v = p[10 * kPlane];
  const float c4v = p[11 * kPlane], c5v = p[12 * kPlane];
  const float c6v = p[13 * kPlane], c7v = p[14 * kPlane];

  const float x = sigmoidf(xr);
  const float y = sigmoidf(yr);
  const float px = x + (float)i;
  const float py = y + (float)j;
  const float pw = expf(w) * s_aw[a];
  const float pl = expf(l) * s_ah[a];
  const float parea = pw * pl;

  float maxiou = 0.0f, iou_own = 0.0f;
  int owner = -1, ncorr = 0;
  for (int t = 0; t < kT; ++t) {
    int vidx = s_idx[t];
    if (vidx < 0) break;  // cumprod-valid is a prefix
    float gx = s_gx[t], gy = s_gy[t], gw = s_gw[t], gl = s_gl[t];
    float mx = fminf(px - pw * 0.5f, gx - gw * 0.5f);
    float Mx = fmaxf(px + pw * 0.5f, gx + gw * 0.5f);
    float my = fminf(py - pl * 0.5f, gy - gl * 0.5f);
    float My = fmaxf(py + pl * 0.5f, gy + gl * 0.5f);
    float cw = pw + gw - (Mx - mx);
    float ch = pl + gl - (My - my);
    float inter = (cw > 0.0f && ch > 0.0f) ? cw * ch : 0.0f;
    float iou = inter / (parea + gw * gl - inter);
    maxiou = fmaxf(maxiou, iou);
    if (vidx == n_global) {
      owner = t;            // last valid match wins (matches in-order scatter)
      iou_own = iou;        // == iou_t for this target => tconf
      if (iou > 0.5f) ncorr++;  // per-target gather semantics
    }
  }

  const float conf = sigmoidf(cr);
  float loss;
  if (owner >= 0) {
    float dx = x - s_tx[owner], dy = y - s_ty[owner];
    float dw = w - s_tw[owner], dl = l - s_tl[owner];
    float di = im - s_tim[owner], dr = re - s_tre[owner];
    float dc = conf - iou_own;
    loss = dx * dx + dy * dy + dw * dw + dl * dl + di * di + dr * dr
         + kObjSq * dc * dc;
    // cross-entropy on the 8 class logits
    float m = fmaxf(fmaxf(fmaxf(c0v, c1v), fmaxf(c2v, c3v)),
                    fmaxf(fmaxf(c4v, c5v), fmaxf(c6v, c7v)));
    float s = expf(c0v - m) + expf(c1v - m) + expf(c2v - m) + expf(c3v - m)
            + expf(c4v - m) + expf(c5v - m) + expf(c6v - m) + expf(c7v - m);
    float lse = m + logf(s);
    int ci = s_tc[owner];
    float csel = c0v;
    csel = (ci == 1) ? c1v : csel;
    csel = (ci == 2) ? c2v : csel;
    csel = (ci == 3) ? c3v : csel;
    csel = (ci == 4) ? c4v : csel;
    csel = (ci == 5) ? c5v : csel;
    csel = (ci == 6) ? c6v : csel;
    csel = (ci == 7) ? c7v : csel;
    loss += lse - csel;
  } else {
    loss = (maxiou > kThresh) ? 0.0f : conf * conf;
  }

  // wave reduce (64-wide), then cross-wave via LDS, one atomic per block
  for (int off = 32; off > 0; off >>= 1) {
    loss += __shfl_down(loss, off, 64);
    ncorr += __shfl_down(ncorr, off, 64);
  }
  const int wv = tid >> 6;
  if ((tid & 63) == 0) { s_red[wv] = loss; s_redi[wv] = ncorr; }
  __syncthreads();
  if (tid == 0) {
    float L = 0.0f;
    int C = 0;
    for (int q = 0; q < kBlk / 64; ++q) { L += s_red[q]; C += s_redi[q]; }
    atomicAdd(d_out + 0, L);
    if (C) atomicAdd(d_out + 1, (float)C);
  }
}

}  // namespace

extern "C" void kernel_launch(void* const* d_in, const int* in_sizes, int n_in,
                              void* d_out, int out_size, void* d_ws,
                              size_t ws_size, hipStream_t stream) {
  const float* output  = (const float*)d_in[0];
  const float* target  = (const float*)d_in[1];
  const float* anchors = (const float*)d_in[2];
  float* outp = (float*)d_out;

  prep_kernel<<<1, 64, 0, stream>>>(target, outp);
  loss_kernel<<<kB * kBlocksPerImg, kBlk, 0, stream>>>(output, target, anchors,
                                                       outp);
}

// Round 2
// 54.381 us; speedup vs baseline: 1.3019x; 1.3019x over previous
//
#include <hip/hip_runtime.h>
#include <math.h>

namespace {

constexpr int kB = 16, kT = 50, kH = 96, kW = 96, kA = 5;
constexpr int kCH = 15;                        // 7 + 8 channels per anchor
constexpr int kPlane = kH * kW;                // 9216
constexpr int kPerImg = kA * kPlane;           // 46080
constexpr int kN = kB * kPerImg;               // 737280
constexpr int kWords = kN / 32;                // 23040 bitmap words
constexpr int kBlk = 256;
constexpr int kBlocksPerImg = kPerImg / kBlk;  // 180 (exact)
constexpr float kObjSq = 100.0f;               // OBJ^2

// d_ws layout (bytes):
//   [0, 92160)          : unsigned bitmap[kWords]   (owner cells)
//   [92160, 104960)     : float4 rec[kB*kT]         {x0, x1, y0, y1}
//   [104960, 108160)    : float  cthr[kB*kT]        0.375*garea (1e30 = invalid)
constexpr size_t kOffRec = 92160;
constexpr size_t kOffC = 104960;

__device__ __forceinline__ float fast_sigmoid(float v) {
  return __builtin_amdgcn_rcpf(1.0f + __expf(-v));
}

// Kernel P (1 block, 1024 threads; wave w handles image w, lanes 0..49):
//  - zero d_out[0..1], compute nGT -> d_out[2]
//  - zero owner bitmap, then set bits at every valid target's scatter idx
//  - write per-target corner records + 0.375*garea for the hot kernel
__global__ __launch_bounds__(1024) void prep_kernel(
    const float* __restrict__ tgt, const float* __restrict__ anc,
    float* __restrict__ d_out, unsigned* __restrict__ bm,
    float4* __restrict__ rec, float* __restrict__ cthr) {
  __shared__ int s_cnt[16];
  const int tid = threadIdx.x;
  for (int i = tid; i < kWords; i += 1024) bm[i] = 0u;

  const int b = tid >> 6, lane = tid & 63;
  const float* tp = tgt + (b * kT + (lane < kT ? lane : 0)) * 7;
  float g1 = tp[1];
  unsigned long long nzm = __ballot((lane < kT) && (g1 != 0.0f));
  bool valid = false;
  int idx = -1;
  if (lane < kT) {
    unsigned long long pre = (1ull << (lane + 1)) - 1ull;
    valid = ((~nzm) & pre) == 0ull;  // cumprod prefix-validity
    float gx = tp[1] * kW, gy = tp[2] * kH, gw = tp[3] * kW, gl = tp[4] * kH;
    float best = -1.0f;
    int bn = 0;
    for (int a = 0; a < kA; ++a) {
      float aw = anc[2 * a], ah = anc[2 * a + 1];
      float inter = fminf(gw, aw) * fminf(gl, ah);
      float iou = inter / (gw * gl + aw * ah - inter);
      if (iou > best) { best = iou; bn = a; }  // first max (argmax)
    }
    int gi = min(max((int)gx, 0), kW - 1);
    int gj = min(max((int)gy, 0), kH - 1);
    idx = ((b * kA + bn) * kH + gj) * kW + gi;
    float4 r;
    float c;
    if (valid) {
      r = make_float4(gx - gw * 0.5f, gx + gw * 0.5f,
                      gy - gl * 0.5f, gy + gl * 0.5f);
      c = 0.375f * (gw * gl);
    } else {  // sentinel: inter -> 0, margin -> -huge
      r = make_float4(1e30f, -1e30f, 1e30f, -1e30f);
      c = 1e30f;
    }
    rec[b * kT + lane] = r;
    cthr[b * kT + lane] = c;
  }
  if (lane == 0) s_cnt[b] = __popcll(__ballot(valid));
  __syncthreads();  // bitmap fully zeroed + s_cnt visible
  if (valid) atomicOr(&bm[idx >> 5], 1u << (idx & 31));
  if (tid == 0) {
    int tot = 0;
    for (int q = 0; q < kB; ++q) tot += s_cnt[q];
    d_out[0] = 0.0f;
    d_out[1] = 0.0f;
    d_out[2] = (float)tot;
  }
}

// Kernel B (hot): noobj conf loss for every cell. Division-free hit test:
//   maxiou > 0.6  <=>  max_t(inter_t - 0.375*garea_t) > 0.375*parea
__global__ __launch_bounds__(kBlk) void noobj_kernel(
    const float* __restrict__ out, const float* __restrict__ anc,
    const unsigned* __restrict__ bm, const float4* __restrict__ rec,
    const float* __restrict__ cthr, float* __restrict__ d_out) {
  __shared__ float4 s_box[kT];
  __shared__ float s_c[kT];
  __shared__ float s_red[kBlk / 64];

  const int tid = threadIdx.x;
  const int b = blockIdx.x / kBlocksPerImg;
  const int nloc = (blockIdx.x % kBlocksPerImg) * kBlk + tid;
  if (tid < kT) {
    s_box[tid] = rec[b * kT + tid];
    s_c[tid] = cthr[b * kT + tid];
  }
  __syncthreads();

  const int a = nloc / kPlane;  // block-uniform (9216 % 256 == 0)
  const int rem = nloc % kPlane;
  const int j = rem / kW;
  const int i = rem % kW;

  const float* p = out + ((size_t)(b * kA + a) * kCH) * kPlane + rem;
  const float xr = p[0];
  const float yr = p[kPlane];
  const float w = p[2 * kPlane];
  const float l = p[3 * kPlane];
  const float cr = p[6 * kPlane];
  const unsigned wd = bm[blockIdx.x * (kBlk / 32) + (tid >> 5)];
  const bool is_owner = (wd >> (tid & 31)) & 1u;

  const float aw = anc[2 * a], ah = anc[2 * a + 1];
  const float px = fast_sigmoid(xr) + (float)i;
  const float py = fast_sigmoid(yr) + (float)j;
  const float pw = __expf(w) * aw;
  const float pl = __expf(l) * ah;
  const float p_x0 = px - pw * 0.5f, p_x1 = px + pw * 0.5f;
  const float p_y0 = py - pl * 0.5f, p_y1 = py + pl * 0.5f;
  const float pthr = 0.375f * (pw * pl);
  const float conf = fast_sigmoid(cr);

  float hh = -1e30f;
#pragma unroll
  for (int t = 0; t < kT; ++t) {
    float4 bx = s_box[t];
    float cw = fminf(p_x1, bx.y) - fmaxf(p_x0, bx.x);
    float ch = fminf(p_y1, bx.w) - fmaxf(p_y0, bx.z);
    float inter = fmaxf(cw, 0.0f) * fmaxf(ch, 0.0f);
    hh = fmaxf(hh, inter - s_c[t]);
  }
  float loss = (is_owner || (hh > pthr)) ? 0.0f : conf * conf;

  for (int off = 32; off > 0; off >>= 1) loss += __shfl_down(loss, off, 64);
  const int wv = tid >> 6;
  if ((tid & 63) == 0) s_red[wv] = loss;
  __syncthreads();
  if (tid == 0) {
    float L = 0.0f;
    for (int q = 0; q < kBlk / 64; ++q) L += s_red[q];
    atomicAdd(d_out + 0, L);
  }
}

// Kernel C: per-target work (<=800 threads total). iou_t + nCorrect for every
// valid target; full owner-cell loss (coord/euler/OBJ-conf/CE) for owners.
__global__ void owner_kernel(const float* __restrict__ out,
                             const float* __restrict__ tgt,
                             const float* __restrict__ anc,
                             float* __restrict__ d_out) {
  __shared__ int s_idx[kT];
  const int b = blockIdx.x, t = threadIdx.x;
  const float* tp = tgt + (b * kT + (t < kT ? t : 0)) * 7;
  float c0 = tp[0], g1 = tp[1], g2 = tp[2], g3 = tp[3], g4 = tp[4];
  float e5 = tp[5], e6 = tp[6];
  unsigned long long nzm = __ballot((t < kT) && (g1 != 0.0f));
  bool valid = false;
  int idx = -1, bn = 0, gi = 0, gj = 0;
  float gx = 0, gy = 0, gw = 0, gl = 0;
  if (t < kT) {
    unsigned long long pre = (1ull << (t + 1)) - 1ull;
    valid = ((~nzm) & pre) == 0ull;
    gx = g1 * kW; gy = g2 * kH; gw = g3 * kW; gl = g4 * kH;
    float best = -1.0f;
    for (int a = 0; a < kA; ++a) {
      float aw = anc[2 * a], ah = anc[2 * a + 1];
      float inter = fminf(gw, aw) * fminf(gl, ah);
      float iou = inter / (gw * gl + aw * ah - inter);
      if (iou > best) { best = iou; bn = a; }
    }
    gi = min(max((int)gx, 0), kW - 1);
    gj = min(max((int)gy, 0), kH - 1);
    idx = ((b * kA + bn) * kH + gj) * kW + gi;
    s_idx[t] = valid ? idx : -1;
  }
  __syncthreads();

  float loss = 0.0f;
  int ncorr = 0;
  if (valid) {
    bool owner = true;  // last valid t with this idx wins (in-order scatter)
    for (int t2 = t + 1; t2 < kT; ++t2)
      if (s_idx[t2] == idx) owner = false;

    const float* p = out + ((size_t)(b * kA + bn) * kCH) * kPlane + gj * kW + gi;
    float xr = p[0], yr = p[kPlane], wr = p[2 * kPlane], lr = p[3 * kPlane];
    float imv = p[4 * kPlane], rev = p[5 * kPlane], cr = p[6 * kPlane];
    float aw = anc[2 * bn], ah = anc[2 * bn + 1];
    float x = 1.0f / (1.0f + expf(-xr));
    float y = 1.0f / (1.0f + expf(-yr));
    float px = x + (float)gi, py = y + (float)gj;
    float pw = expf(wr) * aw, pl = expf(lr) * ah;
    // exact IoU (matches reference formulation)
    float mx = fminf(px - pw * 0.5f, gx - gw * 0.5f);
    float Mx = fmaxf(px + pw * 0.5f, gx + gw * 0.5f);
    float my = fminf(py - pl * 0.5f, gy - gl * 0.5f);
    float My = fmaxf(py + pl * 0.5f, gy + gl * 0.5f);
    float cw = pw + gw - (Mx - mx);
    float ch = pl + gl - (My - my);
    float inter = (cw > 0.0f && ch > 0.0f) ? cw * ch : 0.0f;
    float iou = inter / (pw * pl + gw * gl - inter);
    if (iou > 0.5f) ncorr = 1;

    if (owner) {
      float tx = gx - (float)gi, ty = gy - (float)gj;
      float tw = logf(gw / aw), tl = logf(gl / ah);
      float conf = 1.0f / (1.0f + expf(-cr));
      float dx = x - tx, dy = y - ty, dw = wr - tw, dl = lr - tl;
      float di = imv - e5, dr = rev - e6, dc = conf - iou;
      loss = dx * dx + dy * dy + dw * dw + dl * dl + di * di + dr * dr +
             kObjSq * dc * dc;
      // cross-entropy over the 8 class logits at this cell
      float cv0 = p[7 * kPlane], cv1 = p[8 * kPlane];
      float cv2 = p[9 * kPlane], cv3 = p[10 * kPlane];
      float cv4 = p[11 * kPlane], cv5 = p[12 * kPlane];
      float cv6 = p[13 * kPlane], cv7 = p[14 * kPlane];
      float m = fmaxf(fmaxf(fmaxf(cv0, cv1), fmaxf(cv2, cv3)),
                      fmaxf(fmaxf(cv4, cv5), fmaxf(cv6, cv7)));
      float s = expf(cv0 - m) + expf(cv1 - m) + expf(cv2 - m) +
                expf(cv3 - m) + expf(cv4 - m) + expf(cv5 - m) +
                expf(cv6 - m) + expf(cv7 - m);
      float lse = m + logf(s);
      int ci = min(max((int)c0, 0), 7);
      float csel = cv0;
      csel = (ci == 1) ? cv1 : csel;
      csel = (ci == 2) ? cv2 : csel;
      csel = (ci == 3) ? cv3 : csel;
      csel = (ci == 4) ? cv4 : csel;
      csel = (ci == 5) ? cv5 : csel;
      csel = (ci == 6) ? cv6 : csel;
      csel = (ci == 7) ? cv7 : csel;
      loss += lse - csel;
    }
  }
  for (int off = 32; off > 0; off >>= 1) {
    loss += __shfl_down(loss, off, 64);
    ncorr += __shfl_down(ncorr, off, 64);
  }
  if (t == 0) {
    atomicAdd(d_out + 0, loss);
    if (ncorr) atomicAdd(d_out + 1, (float)ncorr);
  }
}

}  // namespace

extern "C" void kernel_launch(void* const* d_in, const int* in_sizes, int n_in,
                              void* d_out, int out_size, void* d_ws,
                              size_t ws_size, hipStream_t stream) {
  const float* output = (const float*)d_in[0];
  const float* target = (const float*)d_in[1];
  const float* anchors = (const float*)d_in[2];
  float* outp = (float*)d_out;
  char* ws = (char*)d_ws;
  unsigned* bm = (unsigned*)ws;
  float4* rec = (float4*)(ws + kOffRec);
  float* cthr = (float*)(ws + kOffC);

  prep_kernel<<<1, 1024, 0, stream>>>(target, anchors, outp, bm, rec, cthr);
  noobj_kernel<<<kB * kBlocksPerImg, kBlk, 0, stream>>>(output, anchors, bm,
                                                        rec, cthr, outp);
  owner_kernel<<<kB, 64, 0, stream>>>(output, target, anchors, outp);
}